// Round 3
// baseline (368.563 us; speedup 1.0000x reference)
//
#include <hip/hip_runtime.h>

// GCN_84499186582104 — fully fused, one thread per (batch, node).
// B=131072, V=8, NFEAT=32, NHID1=16, NHID12=8, NCLASS=2.
// R3: (1) pooling via LDS h2 exchange + thread-per-gate-row (kills the
//     144-deep shfl chain; bg drops out of softmax), (2) LDS shrunk to
//     13312 B via region aliasing + 128-thread blocks -> 12 blocks/CU,
//     (3) fused Fk/g1 accumulation to cut register pressure.

#define SLOTS 16      // batches per block
#define NTHREADS 128  // 8 threads per batch

__device__ __forceinline__ float grp_sum8(float x) {
    x += __shfl_xor(x, 1);
    x += __shfl_xor(x, 2);
    x += __shfl_xor(x, 4);
    return x;
}

__global__ __launch_bounds__(NTHREADS, 6)
void gcn_fused(const float* __restrict__ x,
               const float* __restrict__ adj,
               const float* __restrict__ edge,
               const float* __restrict__ wb, const float* __restrict__ bb,
               const float* __restrict__ w1, const float* __restrict__ b1,
               const float* __restrict__ w2, const float* __restrict__ b2,
               const float* __restrict__ wg, const float* __restrict__ bg,
               const float* __restrict__ wf, const float* __restrict__ bf,
               float* __restrict__ out, int Btot)
{
    // bufA roles (serialized by barriers): Fk[o*8+v] -> S[o*8+v] -> g2[v*8+n]
    //   -> h2[v*9+n] + type[v*9+8]   (72 floats/slot, 288 B, slot stride = 8 banks)
    // bufB role: g1[v*16+j]          (136 floats/slot: +8 pad)
    __shared__ float bufA[SLOTS * 72];   //  4608 B
    __shared__ float bufB[SLOTS * 136];  //  8704 B   -> total 13312 B/block

    const int tid  = threadIdx.x;
    const int slot = tid >> 3;
    const int v    = tid & 7;
    long long bb_ = (long long)blockIdx.x * SLOTS + slot;
    if (bb_ >= Btot) bb_ = Btot - 1;
    const size_t b = (size_t)bb_;

    float* A  = &bufA[slot * 72];
    float* Bg = &bufB[slot * 136];

    // ---- adj/edge issued first (in flight during Fk/g1 compute) ----
    const float4* ar = (const float4*)(adj  + b * 64 + (size_t)v * 8);
    const float4* er = (const float4*)(edge + b * 64 + (size_t)v * 8);
    const float4 a0 = ar[0], a1 = ar[1];
    const float4 e0 = er[0], e1 = er[1];

    // ---- x row; Fk and g1 accumulated in one pass over c ----
    const float* xr = x + b * 264 + (size_t)v * 33;
    const float type = xr[0];

    float Fk[8];
#pragma unroll
    for (int o = 0; o < 8; ++o) Fk[o] = bb[o];
    float g1[16];
#pragma unroll
    for (int j = 0; j < 16; ++j) g1[j] = 0.f;
#pragma unroll
    for (int c = 0; c < 32; ++c) {
        const float f = xr[1 + c];
#pragma unroll
        for (int o = 0; o < 8; ++o) Fk[o] += f * wb[o * 32 + c];
#pragma unroll
        for (int j = 0; j < 16; ++j) g1[j] += f * w1[c * 16 + j];
    }

    // ---- share Fk (column v) and g1 (row v) ----
#pragma unroll
    for (int o = 0; o < 8; ++o) A[o * 8 + v] = Fk[o];
    {
        float4* gp = (float4*)(Bg + v * 16);
        gp[0] = make_float4(g1[0],  g1[1],  g1[2],  g1[3]);
        gp[1] = make_float4(g1[4],  g1[5],  g1[6],  g1[7]);
        gp[2] = make_float4(g1[8],  g1[9],  g1[10], g1[11]);
        gp[3] = make_float4(g1[12], g1[13], g1[14], g1[15]);
    }
    __syncthreads();   // A: Fk/g1 visible

    // ---- M[o][v] = sum_k Fk[o][k]*Fk[k][v]; softmax over o is thread-local ----
    float M[8];
#pragma unroll
    for (int o = 0; o < 8; ++o) {
        const float4* fr = (const float4*)(A + o * 8);
        const float4 r0 = fr[0], r1 = fr[1];
        M[o] = r0.x * Fk[0] + r0.y * Fk[1] + r0.z * Fk[2] + r0.w * Fk[3]
             + r1.x * Fk[4] + r1.y * Fk[5] + r1.z * Fk[6] + r1.w * Fk[7];
    }
    __syncthreads();   // B: all Fk reads done -> bufA reusable

    float mx = M[0];
#pragma unroll
    for (int o = 1; o < 8; ++o) mx = fmaxf(mx, M[o]);
    float ssum = 0.f;
#pragma unroll
    for (int o = 0; o < 8; ++o) { M[o] = __expf(M[o] - mx); ssum += M[o]; }
    const float sinv = 1.f / ssum;
#pragma unroll
    for (int o = 0; o < 8; ++o) A[o * 8 + v] = M[o] * sinv;   // S column
    __syncthreads();   // C: S visible

    // ---- W row: W[v][w] = adj * (S + edge) ----
    const float4* sr = (const float4*)(A + v * 8);
    const float4 s0 = sr[0], s1 = sr[1];
    float W[8];
    W[0] = a0.x * (s0.x + e0.x);  W[1] = a0.y * (s0.y + e0.y);
    W[2] = a0.z * (s0.z + e0.z);  W[3] = a0.w * (s0.w + e0.w);
    W[4] = a1.x * (s1.x + e1.x);  W[5] = a1.y * (s1.y + e1.y);
    W[6] = a1.z * (s1.z + e1.z);  W[7] = a1.w * (s1.w + e1.w);

    // ---- layer 1: h = leaky(W @ g1 + b1) ----
    float msg1[16];
#pragma unroll
    for (int j = 0; j < 16; ++j) msg1[j] = 0.f;
#pragma unroll
    for (int w = 0; w < 8; ++w) {
        const float wv = W[w];
        const float4* gp = (const float4*)(Bg + w * 16);
        const float4 q0 = gp[0], q1 = gp[1], q2 = gp[2], q3 = gp[3];
        msg1[0]  += wv * q0.x; msg1[1]  += wv * q0.y; msg1[2]  += wv * q0.z; msg1[3]  += wv * q0.w;
        msg1[4]  += wv * q1.x; msg1[5]  += wv * q1.y; msg1[6]  += wv * q1.z; msg1[7]  += wv * q1.w;
        msg1[8]  += wv * q2.x; msg1[9]  += wv * q2.y; msg1[10] += wv * q2.z; msg1[11] += wv * q2.w;
        msg1[12] += wv * q3.x; msg1[13] += wv * q3.y; msg1[14] += wv * q3.z; msg1[15] += wv * q3.w;
    }
    float h[16];
#pragma unroll
    for (int j = 0; j < 16; ++j) {
        const float t = msg1[j] + b1[j];
        h[j] = t > 0.f ? t : 0.01f * t;
    }

    // ---- g2 row: g2[v][n] = dot(h_v, w2[:,n]) ----
    float g2[8];
#pragma unroll
    for (int n = 0; n < 8; ++n) g2[n] = 0.f;
#pragma unroll
    for (int j = 0; j < 16; ++j) {
        const float hv = h[j];
#pragma unroll
        for (int n = 0; n < 8; ++n) g2[n] += hv * w2[j * 8 + n];
    }
    __syncthreads();   // D: all S reads done -> bufA reusable
    {
        float4* gp = (float4*)(A + v * 8);
        gp[0] = make_float4(g2[0], g2[1], g2[2], g2[3]);
        gp[1] = make_float4(g2[4], g2[5], g2[6], g2[7]);
    }
    __syncthreads();   // E: g2 visible

    // ---- layer 2: h2 = leaky(W @ g2 + b2) ----
    float msg2[8];
#pragma unroll
    for (int n = 0; n < 8; ++n) msg2[n] = 0.f;
#pragma unroll
    for (int w = 0; w < 8; ++w) {
        const float wv = W[w];
        const float4* gp = (const float4*)(A + w * 8);
        const float4 q0 = gp[0], q1 = gp[1];
        msg2[0] += wv * q0.x; msg2[1] += wv * q0.y; msg2[2] += wv * q0.z; msg2[3] += wv * q0.w;
        msg2[4] += wv * q1.x; msg2[5] += wv * q1.y; msg2[6] += wv * q1.z; msg2[7] += wv * q1.w;
    }
    float h2[8];
#pragma unroll
    for (int n = 0; n < 8; ++n) {
        const float t = msg2[n] + b2[n];
        h2[n] = t > 0.f ? t : 0.01f * t;
    }
    __syncthreads();   // F: all g2 reads done -> bufA reusable

    // ---- share h2 rows + type (stride 9) ----
#pragma unroll
    for (int n = 0; n < 8; ++n) A[v * 9 + n] = h2[n];
    A[v * 9 + 8] = type;
    __syncthreads();   // G: h2/type visible

    // ---- attention pooling: this thread handles gate-row o = v.
    // logits[o][v'] = bg[o] + mask*d[v']; bg[o] is constant along the softmax
    // axis (v') -> drops out. Masked-out rows have logit 0 (hm row = 0).
    const int o = v;
    float d[8], ty[8], ho[8];
#pragma unroll
    for (int vp = 0; vp < 8; ++vp) {
        const float* hr = A + vp * 9;
        float acc = 0.f;
#pragma unroll
        for (int n = 0; n < 8; ++n) acc += hr[n] * wg[o * 8 + n];
        d[vp] = acc;
        ty[vp] = hr[8];
        ho[vp] = hr[o];
    }
    float xp = 0.f;
#pragma unroll
    for (int t = 0; t < 2; ++t) {
        const float tv = (float)t;
        float l[8];
        float lmx = -1e30f;
#pragma unroll
        for (int vp = 0; vp < 8; ++vp) {
            l[vp] = (ty[vp] == tv) ? d[vp] : 0.f;
            lmx = fmaxf(lmx, l[vp]);
        }
        float esum = 0.f, num = 0.f;
#pragma unroll
        for (int vp = 0; vp < 8; ++vp) {
            const float e = __expf(l[vp] - lmx);
            esum += e;
            num  += (ty[vp] == tv) ? e * ho[vp] : 0.f;
        }
        xp += 0.5f * num / esum;
    }

    // ---- classifier: out[b][n] = bf[n] + sum_o xpool[o]*wf[n][o] ----
    const float y0 = grp_sum8(xp * wf[0 * 8 + o]);
    const float y1 = grp_sum8(xp * wf[1 * 8 + o]);
    if (v == 0) {
        float2* op = (float2*)(out + b * 2);
        *op = make_float2(y0 + bf[0], y1 + bf[1]);
    }
}

extern "C" void kernel_launch(void* const* d_in, const int* in_sizes, int n_in,
                              void* d_out, int out_size, void* d_ws, size_t ws_size,
                              hipStream_t stream) {
    const float* x    = (const float*)d_in[0];
    const float* adj  = (const float*)d_in[1];
    const float* edge = (const float*)d_in[2];
    // d_in[3]=wa, d_in[4]=ba unused by the reference.
    const float* wb   = (const float*)d_in[5];
    const float* bb   = (const float*)d_in[6];
    const float* w1   = (const float*)d_in[7];
    const float* b1   = (const float*)d_in[8];
    const float* w2   = (const float*)d_in[9];
    const float* b2   = (const float*)d_in[10];
    const float* wg   = (const float*)d_in[11];
    const float* bg   = (const float*)d_in[12];
    const float* wf   = (const float*)d_in[13];
    const float* bf   = (const float*)d_in[14];
    float* out = (float*)d_out;

    const int Btot = in_sizes[0] / 264;          // B = 131072
    const int grid = (Btot + SLOTS - 1) / SLOTS; // 8192 blocks

    gcn_fused<<<grid, NTHREADS, 0, stream>>>(x, adj, edge, wb, bb, w1, b1,
                                             w2, b2, wg, bg, wf, bf, out, Btot);
}

// Round 4
// 301.264 us; speedup vs baseline: 1.2234x; 1.2234x over previous
//
#include <hip/hip_runtime.h>

// GCN_84499186582104 — fully fused, one thread per (batch, node).
// B=131072, V=8, NFEAT=32, NHID1=16, NHID12=8, NCLASS=2.
// R4: (1) ZERO __syncthreads — all LDS exchange is between the 8 lanes of a
//     slot, which are always in the same wave (lockstep, DS pipe in-order per
//     wave). wave_barrier() = 0-instruction code-motion fence at handoffs.
//     (2) launch_bounds(128,4): 128-VGPR cap — fixes R3's 40-VGPR scratch
//     spill (WRITE_SIZE 308MB). (3) x row loaded as 1 scalar + 8 float4
//     (dword-aligned) instead of 33 scalar loads -> ~4x fewer L1 line touches.

#define SLOTS 16      // batches per block
#define NTHREADS 128  // 8 threads per batch; slots never span a wave

typedef float4 __attribute__((aligned(4))) f4u;   // dword-aligned float4 load

__device__ __forceinline__ float grp_sum8(float x) {
    x += __shfl_xor(x, 1);
    x += __shfl_xor(x, 2);
    x += __shfl_xor(x, 4);
    return x;
}
__device__ __forceinline__ void wavefence() { __builtin_amdgcn_wave_barrier(); }

__global__ __launch_bounds__(NTHREADS, 4)
void gcn_fused(const float* __restrict__ x,
               const float* __restrict__ adj,
               const float* __restrict__ edge,
               const float* __restrict__ wb, const float* __restrict__ bb,
               const float* __restrict__ w1, const float* __restrict__ b1,
               const float* __restrict__ w2, const float* __restrict__ b2,
               const float* __restrict__ wg, const float* __restrict__ bg,
               const float* __restrict__ wf, const float* __restrict__ bf,
               float* __restrict__ out, int Btot)
{
    // bufA roles (serialized by per-wave DS ordering, slot-private):
    //   Fk[o*8+v] -> S[o*8+v] -> g2[v*8+n] -> h2[v*9+n]+type[v*9+8]
    // bufB role: g1[v*16+j] (slot stride 136: +8 pad)
    __shared__ float bufA[SLOTS * 72];   //  4608 B
    __shared__ float bufB[SLOTS * 136];  //  8704 B  -> 13312 B/block

    const int tid  = threadIdx.x;
    const int slot = tid >> 3;
    const int v    = tid & 7;
    long long bb_ = (long long)blockIdx.x * SLOTS + slot;
    if (bb_ >= Btot) bb_ = Btot - 1;
    const size_t b = (size_t)bb_;

    float* A  = &bufA[slot * 72];
    float* Bg = &bufB[slot * 136];

    // ---- adj/edge issued first (in flight during Fk/g1 compute) ----
    const float4* ar = (const float4*)(adj  + b * 64 + (size_t)v * 8);
    const float4* er = (const float4*)(edge + b * 64 + (size_t)v * 8);
    const float4 a0 = ar[0], a1 = ar[1];
    const float4 e0 = er[0], e1 = er[1];

    // ---- x row: type + 32 features as 8 dword-aligned float4 ----
    const float* xr = x + b * 264 + (size_t)v * 33;
    const float type = xr[0];
    const f4u* xq = (const f4u*)(xr + 1);
    float4 q[8];
#pragma unroll
    for (int k = 0; k < 8; ++k) q[k] = xq[k];

    // ---- Fk column + g1 row, fused accumulation over features ----
    float Fk[8];
#pragma unroll
    for (int o = 0; o < 8; ++o) Fk[o] = bb[o];
    float g1[16];
#pragma unroll
    for (int j = 0; j < 16; ++j) g1[j] = 0.f;
#pragma unroll
    for (int k = 0; k < 8; ++k) {
        const float f[4] = { q[k].x, q[k].y, q[k].z, q[k].w };
#pragma unroll
        for (int u = 0; u < 4; ++u) {
            const int c = 4 * k + u;
            const float fv = f[u];
#pragma unroll
            for (int o = 0; o < 8; ++o) Fk[o] += fv * wb[o * 32 + c];
#pragma unroll
            for (int j = 0; j < 16; ++j) g1[j] += fv * w1[c * 16 + j];
        }
    }

    // ---- share Fk (column v) and g1 (row v) — intra-wave only ----
#pragma unroll
    for (int o = 0; o < 8; ++o) A[o * 8 + v] = Fk[o];
    {
        float4* gp = (float4*)(Bg + v * 16);
        gp[0] = make_float4(g1[0],  g1[1],  g1[2],  g1[3]);
        gp[1] = make_float4(g1[4],  g1[5],  g1[6],  g1[7]);
        gp[2] = make_float4(g1[8],  g1[9],  g1[10], g1[11]);
        gp[3] = make_float4(g1[12], g1[13], g1[14], g1[15]);
    }
    wavefence();

    // ---- M[o][v] = sum_k Fk[o][k]*Fk[k][v]; softmax over o thread-local ----
    float M[8];
#pragma unroll
    for (int o = 0; o < 8; ++o) {
        const float4* fr = (const float4*)(A + o * 8);
        const float4 r0 = fr[0], r1 = fr[1];
        M[o] = r0.x * Fk[0] + r0.y * Fk[1] + r0.z * Fk[2] + r0.w * Fk[3]
             + r1.x * Fk[4] + r1.y * Fk[5] + r1.z * Fk[6] + r1.w * Fk[7];
    }
    wavefence();
    float mx = M[0];
#pragma unroll
    for (int o = 1; o < 8; ++o) mx = fmaxf(mx, M[o]);
    float ssum = 0.f;
#pragma unroll
    for (int o = 0; o < 8; ++o) { M[o] = __expf(M[o] - mx); ssum += M[o]; }
    const float sinv = 1.f / ssum;
#pragma unroll
    for (int o = 0; o < 8; ++o) A[o * 8 + v] = M[o] * sinv;   // S column
    wavefence();

    // ---- W row: W[v][w] = adj * (S + edge) ----
    const float4* sr = (const float4*)(A + v * 8);
    const float4 s0 = sr[0], s1 = sr[1];
    float W[8];
    W[0] = a0.x * (s0.x + e0.x);  W[1] = a0.y * (s0.y + e0.y);
    W[2] = a0.z * (s0.z + e0.z);  W[3] = a0.w * (s0.w + e0.w);
    W[4] = a1.x * (s1.x + e1.x);  W[5] = a1.y * (s1.y + e1.y);
    W[6] = a1.z * (s1.z + e1.z);  W[7] = a1.w * (s1.w + e1.w);

    // ---- layer 1: h = leaky(W @ g1 + b1) ----
    float msg1[16];
#pragma unroll
    for (int j = 0; j < 16; ++j) msg1[j] = 0.f;
#pragma unroll
    for (int w = 0; w < 8; ++w) {
        const float wv = W[w];
        const float4* gp = (const float4*)(Bg + w * 16);
        const float4 q0 = gp[0], q1 = gp[1], q2 = gp[2], q3 = gp[3];
        msg1[0]  += wv * q0.x; msg1[1]  += wv * q0.y; msg1[2]  += wv * q0.z; msg1[3]  += wv * q0.w;
        msg1[4]  += wv * q1.x; msg1[5]  += wv * q1.y; msg1[6]  += wv * q1.z; msg1[7]  += wv * q1.w;
        msg1[8]  += wv * q2.x; msg1[9]  += wv * q2.y; msg1[10] += wv * q2.z; msg1[11] += wv * q2.w;
        msg1[12] += wv * q3.x; msg1[13] += wv * q3.y; msg1[14] += wv * q3.z; msg1[15] += wv * q3.w;
    }
    float h[16];
#pragma unroll
    for (int j = 0; j < 16; ++j) {
        const float t = msg1[j] + b1[j];
        h[j] = t > 0.f ? t : 0.01f * t;
    }

    // ---- g2 row: g2[v][n] = dot(h_v, w2[:,n]) ----
    float g2[8];
#pragma unroll
    for (int n = 0; n < 8; ++n) g2[n] = 0.f;
#pragma unroll
    for (int j = 0; j < 16; ++j) {
        const float hv = h[j];
#pragma unroll
        for (int n = 0; n < 8; ++n) g2[n] += hv * w2[j * 8 + n];
    }
    wavefence();   // all S reads done (program order) -> overwrite A with g2
    {
        float4* gp = (float4*)(A + v * 8);
        gp[0] = make_float4(g2[0], g2[1], g2[2], g2[3]);
        gp[1] = make_float4(g2[4], g2[5], g2[6], g2[7]);
    }
    wavefence();

    // ---- layer 2: h2 = leaky(W @ g2 + b2) ----
    float msg2[8];
#pragma unroll
    for (int n = 0; n < 8; ++n) msg2[n] = 0.f;
#pragma unroll
    for (int w = 0; w < 8; ++w) {
        const float wv = W[w];
        const float4* gp = (const float4*)(A + w * 8);
        const float4 q0 = gp[0], q1 = gp[1];
        msg2[0] += wv * q0.x; msg2[1] += wv * q0.y; msg2[2] += wv * q0.z; msg2[3] += wv * q0.w;
        msg2[4] += wv * q1.x; msg2[5] += wv * q1.y; msg2[6] += wv * q1.z; msg2[7] += wv * q1.w;
    }
    float h2[8];
#pragma unroll
    for (int n = 0; n < 8; ++n) {
        const float t = msg2[n] + b2[n];
        h2[n] = t > 0.f ? t : 0.01f * t;
    }
    wavefence();   // all g2 reads done -> overwrite A with h2/type

    // ---- share h2 rows + type (stride 9) ----
#pragma unroll
    for (int n = 0; n < 8; ++n) A[v * 9 + n] = h2[n];
    A[v * 9 + 8] = type;
    wavefence();

    // ---- attention pooling: thread handles gate-row o = v.
    // bg[o] constant along softmax axis -> drops out. Masked-out rows: logit 0.
    const int o = v;
    float d[8], ty[8], ho[8];
#pragma unroll
    for (int vp = 0; vp < 8; ++vp) {
        const float* hr = A + vp * 9;
        float acc = 0.f;
#pragma unroll
        for (int n = 0; n < 8; ++n) acc += hr[n] * wg[o * 8 + n];
        d[vp] = acc;
        ty[vp] = hr[8];
        ho[vp] = hr[o];
    }
    float xp = 0.f;
#pragma unroll
    for (int t = 0; t < 2; ++t) {
        const float tv = (float)t;
        float l[8];
        float lmx = -1e30f;
#pragma unroll
        for (int vp = 0; vp < 8; ++vp) {
            l[vp] = (ty[vp] == tv) ? d[vp] : 0.f;
            lmx = fmaxf(lmx, l[vp]);
        }
        float esum = 0.f, num = 0.f;
#pragma unroll
        for (int vp = 0; vp < 8; ++vp) {
            const float e = __expf(l[vp] - lmx);
            esum += e;
            num  += (ty[vp] == tv) ? e * ho[vp] : 0.f;
        }
        xp += 0.5f * num / esum;
    }

    // ---- classifier ----
    const float y0 = grp_sum8(xp * wf[0 * 8 + o]);
    const float y1 = grp_sum8(xp * wf[1 * 8 + o]);
    if (v == 0) {
        float2* op = (float2*)(out + b * 2);
        *op = make_float2(y0 + bf[0], y1 + bf[1]);
    }
}

extern "C" void kernel_launch(void* const* d_in, const int* in_sizes, int n_in,
                              void* d_out, int out_size, void* d_ws, size_t ws_size,
                              hipStream_t stream) {
    const float* x    = (const float*)d_in[0];
    const float* adj  = (const float*)d_in[1];
    const float* edge = (const float*)d_in[2];
    // d_in[3]=wa, d_in[4]=ba unused by the reference.
    const float* wb   = (const float*)d_in[5];
    const float* bb   = (const float*)d_in[6];
    const float* w1   = (const float*)d_in[7];
    const float* b1   = (const float*)d_in[8];
    const float* w2   = (const float*)d_in[9];
    const float* b2   = (const float*)d_in[10];
    const float* wg   = (const float*)d_in[11];
    const float* bg   = (const float*)d_in[12];
    const float* wf   = (const float*)d_in[13];
    const float* bf   = (const float*)d_in[14];
    float* out = (float*)d_out;

    const int Btot = in_sizes[0] / 264;          // B = 131072
    const int grid = (Btot + SLOTS - 1) / SLOTS; // 8192 blocks

    gcn_fused<<<grid, NTHREADS, 0, stream>>>(x, adj, edge, wb, bb, w1, b1,
                                             w2, b2, wg, bg, wf, bf, out, Btot);
}